// Round 2
// baseline (17155.101 us; speedup 1.0000x reference)
//
#include <hip/hip_runtime.h>

typedef unsigned short ushort_t;
typedef __attribute__((ext_vector_type(8))) short short8;
typedef __attribute__((ext_vector_type(4))) float floatx4;

// Problem constants: V=50000, E=512, H=512, L=32, B=64, T=512
// Chunked: NC=8 chunks of CS=64 steps.

__device__ __forceinline__ float bf2f(ushort_t u) {
  unsigned x = ((unsigned)u) << 16;
  return __builtin_bit_cast(float, x);
}
__device__ __forceinline__ ushort_t f2bf(float f) {
  unsigned x = __builtin_bit_cast(unsigned, f);
  x += 0x7FFFu + ((x >> 16) & 1u);
  return (ushort_t)(x >> 16);
}
__device__ __forceinline__ float sigf(float x) { return 1.0f / (1.0f + __expf(-x)); }
__device__ __forceinline__ float tanhf_(float x) { return 1.0f - 2.0f / (__expf(2.0f * x) + 1.0f); }

// ---------------- workspace layout (bytes), total ~173.6 MiB ----------------
static const size_t OFF_A    = 0;            // union: x_bf [32768][512] bf16 (phases 1-2)
                                             //        out1 [32768][1024] bf16 (phases 3-4)   67108864
static const size_t OFF_OUT0 = 67108864;     // out0 [32768][1024] bf16                      67108864
static const size_t OFF_XG   = 134217728;    // xg0c+xg1c [64][64][2048] bf16 each (33554432)
                                             // emis [32768][32] f32 aliases this in phase 4
static const size_t OFF_WIH0 = 167772160;    // wih0_bf [2][2048][512] bf16    4194304
static const size_t OFF_WIH1 = 171966464;    // wih1_bf [2][2048][1024] bf16   8388608
static const size_t OFF_BIAS = 180355072;    // bias [2][2][2048] f32          32768
static const size_t OFF_WOUT = 180387840;    // w_out frag-major bf16          65536
static const size_t OFF_HC   = 180453376;    // h exchange [2 layers][2 dir][2 buf][64][1024] bf16  1048576
static const size_t OFF_CST  = 181501952;    // c state [2 layers][2 dir][64][512] f32        524288
static const size_t OFF_BAR  = 182026240;    // 4 barrier counters             256
static const size_t OFF_NUM  = 182026496;    // num[64] f32                    256
static const size_t OFF_PERB = 182026752;    // perb[64] f32                   256
static const size_t OFF_END  = 182027008;

// ---------------- prep: cast w_ih to bf16, combine biases, wout frag-major ----------------
__global__ void prep_kernel(const float* __restrict__ w_ih0, const float* __restrict__ w_ih1,
                            const float* __restrict__ b_ih, const float* __restrict__ b_hh,
                            const float* __restrict__ w_out,
                            ushort_t* __restrict__ wih0_bf, ushort_t* __restrict__ wih1_bf,
                            float* __restrict__ bias, ushort_t* __restrict__ wout_bf) {
  int idx = blockIdx.x * 256 + threadIdx.x;
  int stride = gridDim.x * 256;
  for (int i = idx; i < 2097152; i += stride) wih0_bf[i] = f2bf(w_ih0[i]);
  for (int i = idx; i < 4194304; i += stride) wih1_bf[i] = f2bf(w_ih1[i]);
  for (int i = idx; i < 8192; i += stride) bias[i] = b_ih[i] + b_hh[i];
  // w_out [1024][32] -> 16x16x32 B-operand frag-major:
  // i = ((nt*32+kb)*64 + Ls)*8 + j ; lane Ls holds n=nt*16+(Ls&15), k=kb*32+((Ls>>4)&3)*8+j
  for (int i = idx; i < 32768; i += stride) {
    int j = i & 7, Ls = (i >> 3) & 63, kb = (i >> 9) & 31, nt = i >> 14;
    int n = nt * 16 + (Ls & 15);
    int k = kb * 32 + ((Ls >> 4) & 3) * 8 + j;
    wout_bf[i] = f2bf(w_out[k * 32 + n]);
  }
}

// ---------------- embedding gather + cast ----------------
__global__ void embed_kernel(const int* __restrict__ datas, const float* __restrict__ emb,
                             ushort_t* __restrict__ x_bf) {
  int idx = blockIdx.x * 256 + threadIdx.x;  // < 2097152 = 32768*64
  int row = idx >> 6, sub = idx & 63;
  int tok = datas[row];
  const float4* ep = (const float4*)(emb + (size_t)tok * 512 + sub * 8);
  float4 f0 = ep[0], f1 = ep[1];
  short8 v;
  v[0] = (short)f2bf(f0.x); v[1] = (short)f2bf(f0.y);
  v[2] = (short)f2bf(f0.z); v[3] = (short)f2bf(f0.w);
  v[4] = (short)f2bf(f1.x); v[5] = (short)f2bf(f1.y);
  v[6] = (short)f2bf(f1.z); v[7] = (short)f2bf(f1.w);
  *(short8*)(x_bf + (size_t)row * 512 + sub * 8) = v;
}

// ---------------- chunked input-projection GEMM ----------------
// For one chunk: per dir, computes xg[ts][b][2048] = A[row(b,t0+ts), :K] @ W_dir[2048,K]^T + bias
// grid = 1024: dir = gid>>9; within 512: mt (32) x ntt (16); A row = b*512 + t0 + ts.
__global__ __launch_bounds__(256) void gemm_chunk(const ushort_t* __restrict__ A, int K,
                                                  const ushort_t* __restrict__ W,
                                                  const float* __restrict__ biasL,
                                                  ushort_t* __restrict__ xg0c,
                                                  ushort_t* __restrict__ xg1c,
                                                  int t00, int t01) {
  __shared__ alignas(16) ushort_t alds[512 * 8];
  __shared__ alignas(16) ushort_t blds[512 * 8];
  int gid = blockIdx.x;
  int dir = gid >> 9, r = gid & 511;
  int mt = r & 31, ntt = r >> 5;
  int t0 = dir ? t01 : t00;
  const ushort_t* Bm = W + (size_t)dir * 2048 * K;
  const float* bptr = biasL + dir * 2048;
  ushort_t* xg = dir ? xg1c : xg0c;
  int bm0 = mt * 128, bn0 = ntt * 128;
  int tid = threadIdx.x, L = tid & 63, w = tid >> 6;
  int wm = w & 1, wn = w >> 1;
  floatx4 acc[4][4] = {};
  for (int k0 = 0; k0 < K; k0 += 32) {
    __syncthreads();
    #pragma unroll
    for (int rep = 0; rep < 2; rep++) {
      int slot = rep * 256 + tid;  // 0..511
      int t8 = slot >> 6, Ls = slot & 63;
      int col = k0 + (Ls >> 4) * 8;
      int mp = bm0 + t8 * 16 + (Ls & 15);                 // m' in [0,4096)
      int Arow = (mp >> 6) * 512 + t0 + (mp & 63);        // b*512 + t
      *(short8*)&alds[slot * 8] = *(const short8*)&A[(size_t)Arow * K + col];
      int rowb = bn0 + t8 * 16 + (Ls & 15);               // gate col in [0,2048)
      *(short8*)&blds[slot * 8] = *(const short8*)&Bm[(size_t)rowb * K + col];
    }
    __syncthreads();
    short8 af[4];
    #pragma unroll
    for (int a = 0; a < 4; a++) af[a] = *(const short8*)&alds[((wm * 4 + a) * 64 + L) * 8];
    #pragma unroll
    for (int bq = 0; bq < 4; bq++) {
      short8 bfr = *(const short8*)&blds[((wn * 4 + bq) * 64 + L) * 8];
      #pragma unroll
      for (int a = 0; a < 4; a++)
        acc[a][bq] = __builtin_amdgcn_mfma_f32_16x16x32_bf16(af[a], bfr, acc[a][bq], 0, 0, 0);
    }
  }
  int lm = L >> 4, ln = L & 15;
  #pragma unroll
  for (int bq = 0; bq < 4; bq++) {
    int n = bn0 + (wn * 4 + bq) * 16 + ln;  // [0,2048)
    float bv = bptr[n];
    #pragma unroll
    for (int a = 0; a < 4; a++) {
      #pragma unroll
      for (int rr = 0; rr < 4; rr++) {
        int m = bm0 + (wm * 4 + a) * 16 + lm * 4 + rr;
        int b = m >> 6, ts = m & 63;
        xg[((size_t)(ts * 64 + b)) * 2048 + n] = f2bf(acc[a][bq][rr] + bv);
      }
    }
  }
}

// ---------------- recurrent LSTM, one chunk of 64 steps (both dirs; 64 blocks) ----------------
// block: dir d = bid>>5, slice g = bid&31 owns h-cols [g*16,g*16+16) => gate cols q*512+g*16+jj.
// W_hh slice converted f32->bf16 into LDS each launch (frag-major, 64KB).
// h exchanged via padded global parity buffers + per-dir cumulative spin barrier.
__global__ __launch_bounds__(256) void lstm_chunk(const ushort_t* __restrict__ xg0c,
                                                  const ushort_t* __restrict__ xg1c,
                                                  const float* __restrict__ whh_f,  // layer base [2][2048][512] f32
                                                  ushort_t* __restrict__ hcL,       // [2 dir][2 buf][64][1024]
                                                  float* __restrict__ cstL,         // [2 dir][64][512]
                                                  ushort_t* __restrict__ outL,      // [32768][1024], col offset d*512
                                                  int* __restrict__ bar, int c) {
  __shared__ alignas(16) ushort_t wlds[32768];  // 64 KB
  int bid = blockIdx.x, d = bid >> 5, g = bid & 31, j0 = g * 16;
  int tid = threadIdx.x, L = tid & 63, w = tid >> 6;
  const float* wptr = whh_f + (size_t)d * 2048 * 512;
  #pragma unroll
  for (int it = 0; it < 16; it++) {
    int slot = it * 256 + tid;  // 0..4095
    int q = slot >> 10, kb = (slot >> 6) & 15, Ls = slot & 63;
    int gcol = q * 512 + j0 + (Ls & 15);
    int k = kb * 32 + (Ls >> 4) * 8;
    const float* src = wptr + (size_t)gcol * 512 + k;
    float4 f0 = *(const float4*)src;
    float4 f1 = *(const float4*)(src + 4);
    short8 v;
    v[0] = (short)f2bf(f0.x); v[1] = (short)f2bf(f0.y);
    v[2] = (short)f2bf(f0.z); v[3] = (short)f2bf(f0.w);
    v[4] = (short)f2bf(f1.x); v[5] = (short)f2bf(f1.y);
    v[6] = (short)f2bf(f1.z); v[7] = (short)f2bf(f1.w);
    *(short8*)&wlds[slot * 8] = v;
  }
  __syncthreads();
  const ushort_t* xgd = d ? xg1c : xg0c;
  ushort_t* hcd = hcL + (size_t)d * 2 * 64 * 1024;
  int q8 = L >> 4;
  int mbase = w * 16 + q8 * 4;   // C-layout batch row base
  int jj = L & 15;
  int arow = w * 16 + jj;        // A-layout batch row
  int aoff = (q8 >> 1) * 32 + (q8 & 1) * 8;  // k-offset within padded h row
  // load carry state (zeros for chunk 0 via memset)
  float cv[4];
  #pragma unroll
  for (int rr = 0; rr < 4; rr++) cv[rr] = cstL[(size_t)d * 32768 + (mbase + rr) * 512 + j0 + jj];
  int* bptr = bar + d;
  for (int sl = 0; sl < 64; sl++) {
    int s = c * 64 + sl;
    int t = d ? (511 - s) : s;
    int ts = d ? (63 - sl) : sl;
    const ushort_t* hread = hcd + (size_t)(s & 1) * 64 * 1024;
    ushort_t* hwrite = hcd + (size_t)((s + 1) & 1) * 64 * 1024;
    // xg for this step
    ushort_t xgu[4][4];
    #pragma unroll
    for (int rr = 0; rr < 4; rr++) {
      const ushort_t* xrow = xgd + ((size_t)(ts * 64 + mbase + rr)) * 2048 + j0 + jj;
      #pragma unroll
      for (int q = 0; q < 4; q++) xgu[q][rr] = xrow[q * 512];
    }
    floatx4 acc[4] = {};
    #pragma unroll 4
    for (int kb = 0; kb < 16; kb++) {
      short8 a = *(const short8*)&hread[(size_t)arow * 1024 + kb * 64 + aoff];
      #pragma unroll
      for (int q = 0; q < 4; q++) {
        short8 bfr = *(const short8*)&wlds[((q * 16 + kb) * 64 + L) * 8];
        acc[q] = __builtin_amdgcn_mfma_f32_16x16x32_bf16(a, bfr, acc[q], 0, 0, 0);
      }
    }
    #pragma unroll
    for (int rr = 0; rr < 4; rr++) {
      float ii = acc[0][rr] + bf2f(xgu[0][rr]);
      float ff = acc[1][rr] + bf2f(xgu[1][rr]);
      float gg = acc[2][rr] + bf2f(xgu[2][rr]);
      float oo = acc[3][rr] + bf2f(xgu[3][rr]);
      float cc = sigf(ff) * cv[rr] + sigf(ii) * tanhf_(gg);
      cv[rr] = cc;
      ushort_t hb = f2bf(sigf(oo) * tanhf_(cc));
      int m = mbase + rr;
      hwrite[(size_t)m * 1024 + g * 32 + jj] = hb;
      outL[((size_t)m * 512 + t) * 1024 + (d << 9) + j0 + jj] = hb;
    }
    if (sl != 63) {
      __threadfence();   // EVERY thread: release its h stores device-wide (cross-XCD L2 writeback)
      __syncthreads();
      if (tid == 0) {
        __hip_atomic_fetch_add(bptr, 1, __ATOMIC_RELEASE, __HIP_MEMORY_SCOPE_AGENT);
        int target = 32 * (63 * c + sl + 1);
        int guard = 0;
        while (__hip_atomic_load(bptr, __ATOMIC_RELAXED, __HIP_MEMORY_SCOPE_AGENT) < target &&
               guard < (1 << 17)) guard++;
        __threadfence();  // acquire: invalidate stale L1/L2 lines before h reads
      }
      __syncthreads();
    }
  }
  // save carry state for next chunk
  #pragma unroll
  for (int rr = 0; rr < 4; rr++) cstL[(size_t)d * 32768 + (mbase + rr) * 512 + j0 + jj] = cv[rr];
}

// ---------------- emissions: [32768,1024] @ [1024,32] + b_out ----------------
__global__ __launch_bounds__(256) void emis_kernel(const ushort_t* __restrict__ out1,
                                                   const ushort_t* __restrict__ wout_bf,
                                                   const float* __restrict__ b_out,
                                                   float* __restrict__ emis) {
  int tid = threadIdx.x, L = tid & 63, w = tid >> 6;
  int bm0 = blockIdx.x * 128;
  int q8 = L >> 4, ln = L & 15;
  floatx4 acc[2][2] = {};
  #pragma unroll 4
  for (int kb = 0; kb < 32; kb++) {
    short8 a0 = *(const short8*)&out1[(size_t)(bm0 + (w * 2 + 0) * 16 + ln) * 1024 + kb * 32 + q8 * 8];
    short8 a1 = *(const short8*)&out1[(size_t)(bm0 + (w * 2 + 1) * 16 + ln) * 1024 + kb * 32 + q8 * 8];
    #pragma unroll
    for (int nt = 0; nt < 2; nt++) {
      short8 bfr = *(const short8*)&wout_bf[((size_t)(nt * 32 + kb) * 64 + L) * 8];
      acc[0][nt] = __builtin_amdgcn_mfma_f32_16x16x32_bf16(a0, bfr, acc[0][nt], 0, 0, 0);
      acc[1][nt] = __builtin_amdgcn_mfma_f32_16x16x32_bf16(a1, bfr, acc[1][nt], 0, 0, 0);
    }
  }
  #pragma unroll
  for (int mt = 0; mt < 2; mt++) {
    #pragma unroll
    for (int nt = 0; nt < 2; nt++) {
      int n = nt * 16 + ln;
      float bv = b_out[n];
      #pragma unroll
      for (int rr = 0; rr < 4; rr++) {
        int m = bm0 + (w * 2 + mt) * 16 + q8 * 4 + rr;
        emis[(size_t)m * 32 + n] = acc[mt][nt][rr] + bv;
      }
    }
  }
}

// ---------------- CRF numerator ----------------
__global__ void num_kernel(const int* __restrict__ labels, const float* __restrict__ emis,
                           const float* __restrict__ trans, const float* __restrict__ cstart,
                           const float* __restrict__ cend, float* __restrict__ num) {
  int b = blockIdx.x, tid = threadIdx.x;
  float s = 0.f;
  for (int t = tid; t < 512; t += 64) {
    int tag = labels[b * 512 + t];
    s += emis[(size_t)(b * 512 + t) * 32 + tag];
    if (t < 511) s += trans[tag * 32 + labels[b * 512 + t + 1]];
  }
  #pragma unroll
  for (int off = 32; off > 0; off >>= 1) s += __shfl_xor(s, off, 64);
  if (tid == 0) num[b] = s + cstart[labels[b * 512]] + cend[labels[b * 512 + 511]];
}

// ---------------- CRF forward scan ----------------
__global__ __launch_bounds__(64) void fwd_kernel(const float* __restrict__ emis,
                                                 const float* __restrict__ trans,
                                                 const float* __restrict__ cstart,
                                                 const float* __restrict__ cend,
                                                 const float* __restrict__ num,
                                                 float* __restrict__ perb) {
  int b = blockIdx.x, tid = threadIdx.x, j = tid & 31;
  float trj[32];
  #pragma unroll
  for (int i = 0; i < 32; i++) trj[i] = trans[i * 32 + j];
  float alpha = cstart[j] + emis[(size_t)(b * 512) * 32 + j];
  for (int t = 1; t < 512; t++) {
    float e = emis[(size_t)(b * 512 + t) * 32 + j];
    float m = -1e30f;
    float v[32];
    #pragma unroll
    for (int i = 0; i < 32; i++) {
      v[i] = __shfl(alpha, i, 32) + trj[i];
      m = fmaxf(m, v[i]);
    }
    float s = 0.f;
    #pragma unroll
    for (int i = 0; i < 32; i++) s += __expf(v[i] - m);
    alpha = __logf(s) + m + e;
  }
  float z = alpha + cend[j];
  float m2 = z;
  #pragma unroll
  for (int off = 16; off > 0; off >>= 1) m2 = fmaxf(m2, __shfl_xor(m2, off, 32));
  float s2 = __expf(z - m2);
  #pragma unroll
  for (int off = 16; off > 0; off >>= 1) s2 += __shfl_xor(s2, off, 32);
  if (tid == 0) perb[b] = num[b] - (__logf(s2) + m2);
}

__global__ void final_kernel(const float* __restrict__ perb, float* __restrict__ out) {
  int tid = threadIdx.x;
  float s = perb[tid];
  #pragma unroll
  for (int off = 32; off > 0; off >>= 1) s += __shfl_xor(s, off, 64);
  if (tid == 0) out[0] = -s;
}

// ---------------- host launch ----------------
extern "C" void kernel_launch(void* const* d_in, const int* in_sizes, int n_in,
                              void* d_out, int out_size, void* d_ws, size_t ws_size,
                              hipStream_t stream) {
  (void)in_sizes; (void)n_in; (void)out_size; (void)ws_size;
  const int* datas = (const int*)d_in[0];
  const int* labels = (const int*)d_in[1];
  const float* emb = (const float*)d_in[2];
  const float* w_ih0 = (const float*)d_in[3];
  const float* w_ih1 = (const float*)d_in[4];
  const float* w_hh = (const float*)d_in[5];
  const float* b_ih = (const float*)d_in[6];
  const float* b_hh = (const float*)d_in[7];
  const float* w_out = (const float*)d_in[8];
  const float* b_out = (const float*)d_in[9];
  const float* cstart = (const float*)d_in[10];
  const float* cend = (const float*)d_in[11];
  const float* ctrans = (const float*)d_in[12];

  char* ws = (char*)d_ws;
  ushort_t* x_bf = (ushort_t*)(ws + OFF_A);        // phases 1-2
  ushort_t* out1 = (ushort_t*)(ws + OFF_A);        // phases 3-4 (alias)
  ushort_t* out0 = (ushort_t*)(ws + OFF_OUT0);
  ushort_t* xg0c = (ushort_t*)(ws + OFF_XG);
  ushort_t* xg1c = (ushort_t*)(ws + OFF_XG + 16777216);
  float* emis = (float*)(ws + OFF_XG);             // phase 4 (alias)
  ushort_t* wih0_bf = (ushort_t*)(ws + OFF_WIH0);
  ushort_t* wih1_bf = (ushort_t*)(ws + OFF_WIH1);
  float* bias = (float*)(ws + OFF_BIAS);
  ushort_t* wout_bf = (ushort_t*)(ws + OFF_WOUT);
  ushort_t* hc0 = (ushort_t*)(ws + OFF_HC);
  ushort_t* hc1 = hc0 + 262144;
  float* cst0 = (float*)(ws + OFF_CST);
  float* cst1 = cst0 + 65536;
  int* bar = (int*)(ws + OFF_BAR);
  float* numb = (float*)(ws + OFF_NUM);
  float* perb = (float*)(ws + OFF_PERB);

  // zero h parity buffers, carry state, barrier counters, num/perb
  hipMemsetAsync(ws + OFF_HC, 0, OFF_END - OFF_HC, stream);

  prep_kernel<<<2048, 256, 0, stream>>>(w_ih0, w_ih1, b_ih, b_hh, w_out,
                                        wih0_bf, wih1_bf, bias, wout_bf);
  embed_kernel<<<8192, 256, 0, stream>>>(datas, emb, x_bf);

  // layer 0 (A = x_bf, K=512)
  for (int c = 0; c < 8; c++) {
    gemm_chunk<<<1024, 256, 0, stream>>>(x_bf, 512, wih0_bf, bias, xg0c, xg1c,
                                         c * 64, (7 - c) * 64);
    lstm_chunk<<<64, 256, 0, stream>>>(xg0c, xg1c, w_hh, hc0, cst0, out0, bar, c);
  }
  // layer 1 (A = out0, K=1024)
  for (int c = 0; c < 8; c++) {
    gemm_chunk<<<1024, 256, 0, stream>>>(out0, 1024, wih1_bf, bias + 4096, xg0c, xg1c,
                                         c * 64, (7 - c) * 64);
    lstm_chunk<<<64, 256, 0, stream>>>(xg0c, xg1c, w_hh + 2097152, hc1, cst1, out1,
                                       bar + 2, c);
  }

  // emissions + CRF
  emis_kernel<<<256, 256, 0, stream>>>(out1, wout_bf, b_out, emis);
  num_kernel<<<64, 64, 0, stream>>>(labels, emis, ctrans, cstart, cend, numb);
  fwd_kernel<<<64, 64, 0, stream>>>(emis, ctrans, cstart, cend, numb, perb);
  final_kernel<<<1, 64, 0, stream>>>(perb, (float*)d_out);
}

// Round 3
// 6960.249 us; speedup vs baseline: 2.4647x; 2.4647x over previous
//
#include <hip/hip_runtime.h>

typedef unsigned short ushort_t;
typedef unsigned long long u64_t;
typedef __attribute__((ext_vector_type(8))) short short8;
typedef __attribute__((ext_vector_type(4))) float floatx4;

// Problem constants: V=50000, E=512, H=512, L=32, B=64, T=512
// Chunked: NC=8 chunks of CS=64 steps.

__device__ __forceinline__ float bf2f(ushort_t u) {
  unsigned x = ((unsigned)u) << 16;
  return __builtin_bit_cast(float, x);
}
__device__ __forceinline__ ushort_t f2bf(float f) {
  unsigned x = __builtin_bit_cast(unsigned, f);
  x += 0x7FFFu + ((x >> 16) & 1u);
  return (ushort_t)(x >> 16);
}
__device__ __forceinline__ float sigf(float x) { return 1.0f / (1.0f + __expf(-x)); }
__device__ __forceinline__ float tanhf_(float x) { return 1.0f - 2.0f / (__expf(2.0f * x) + 1.0f); }

// ---------------- workspace layout (bytes), total ~173.6 MiB ----------------
static const size_t OFF_A    = 0;            // union: x_bf [32768][512] bf16 (phases 1-2)
                                             //        out1 [32768][1024] bf16 (phases 3-4)   67108864
static const size_t OFF_OUT0 = 67108864;     // out0 [32768][1024] bf16                      67108864
static const size_t OFF_XG   = 134217728;    // xg0c+xg1c [64][64][2048] bf16 each (33554432)
                                             // emis [32768][32] f32 aliases this in phase 4
static const size_t OFF_WIH0 = 167772160;    // wih0_bf [2][2048][512] bf16    4194304
static const size_t OFF_WIH1 = 171966464;    // wih1_bf [2][2048][1024] bf16   8388608
static const size_t OFF_BIAS = 180355072;    // bias [2][2][2048] f32          32768
static const size_t OFF_WOUT = 180387840;    // w_out frag-major bf16          65536
static const size_t OFF_HC   = 180453376;    // h exchange [2 layers][2 dir][2 buf][32768] bf16 frag-major
static const size_t OFF_CST  = 181501952;    // c state [2 layers][2 dir][64][512] f32        524288
static const size_t OFF_BAR  = 182026240;    // 4 barrier counters             256
static const size_t OFF_NUM  = 182026496;    // num[64] f32                    256
static const size_t OFF_PERB = 182026752;    // perb[64] f32                   256
static const size_t OFF_END  = 182027008;

// ---------------- prep: cast w_ih to bf16, combine biases, wout frag-major ----------------
__global__ void prep_kernel(const float* __restrict__ w_ih0, const float* __restrict__ w_ih1,
                            const float* __restrict__ b_ih, const float* __restrict__ b_hh,
                            const float* __restrict__ w_out,
                            ushort_t* __restrict__ wih0_bf, ushort_t* __restrict__ wih1_bf,
                            float* __restrict__ bias, ushort_t* __restrict__ wout_bf) {
  int idx = blockIdx.x * 256 + threadIdx.x;
  int stride = gridDim.x * 256;
  for (int i = idx; i < 2097152; i += stride) wih0_bf[i] = f2bf(w_ih0[i]);
  for (int i = idx; i < 4194304; i += stride) wih1_bf[i] = f2bf(w_ih1[i]);
  for (int i = idx; i < 8192; i += stride) bias[i] = b_ih[i] + b_hh[i];
  // w_out [1024][32] -> 16x16x32 B-operand frag-major
  for (int i = idx; i < 32768; i += stride) {
    int j = i & 7, Ls = (i >> 3) & 63, kb = (i >> 9) & 31, nt = i >> 14;
    int n = nt * 16 + (Ls & 15);
    int k = kb * 32 + ((Ls >> 4) & 3) * 8 + j;
    wout_bf[i] = f2bf(w_out[k * 32 + n]);
  }
}

// ---------------- embedding gather + cast ----------------
__global__ void embed_kernel(const int* __restrict__ datas, const float* __restrict__ emb,
                             ushort_t* __restrict__ x_bf) {
  int idx = blockIdx.x * 256 + threadIdx.x;  // < 2097152 = 32768*64
  int row = idx >> 6, sub = idx & 63;
  int tok = datas[row];
  const float4* ep = (const float4*)(emb + (size_t)tok * 512 + sub * 8);
  float4 f0 = ep[0], f1 = ep[1];
  short8 v;
  v[0] = (short)f2bf(f0.x); v[1] = (short)f2bf(f0.y);
  v[2] = (short)f2bf(f0.z); v[3] = (short)f2bf(f0.w);
  v[4] = (short)f2bf(f1.x); v[5] = (short)f2bf(f1.y);
  v[6] = (short)f2bf(f1.z); v[7] = (short)f2bf(f1.w);
  *(short8*)(x_bf + (size_t)row * 512 + sub * 8) = v;
}

// ---------------- chunked input-projection GEMM ----------------
__global__ __launch_bounds__(256) void gemm_chunk(const ushort_t* __restrict__ A, int K,
                                                  const ushort_t* __restrict__ W,
                                                  const float* __restrict__ biasL,
                                                  ushort_t* __restrict__ xg0c,
                                                  ushort_t* __restrict__ xg1c,
                                                  int t00, int t01) {
  __shared__ alignas(16) ushort_t alds[512 * 8];
  __shared__ alignas(16) ushort_t blds[512 * 8];
  int gid = blockIdx.x;
  int dir = gid >> 9, r = gid & 511;
  int mt = r & 31, ntt = r >> 5;
  int t0 = dir ? t01 : t00;
  const ushort_t* Bm = W + (size_t)dir * 2048 * K;
  const float* bptr = biasL + dir * 2048;
  ushort_t* xg = dir ? xg1c : xg0c;
  int bm0 = mt * 128, bn0 = ntt * 128;
  int tid = threadIdx.x, L = tid & 63, w = tid >> 6;
  int wm = w & 1, wn = w >> 1;
  floatx4 acc[4][4] = {};
  for (int k0 = 0; k0 < K; k0 += 32) {
    __syncthreads();
    #pragma unroll
    for (int rep = 0; rep < 2; rep++) {
      int slot = rep * 256 + tid;  // 0..511
      int t8 = slot >> 6, Ls = slot & 63;
      int col = k0 + (Ls >> 4) * 8;
      int mp = bm0 + t8 * 16 + (Ls & 15);                 // m' in [0,4096)
      int Arow = (mp >> 6) * 512 + t0 + (mp & 63);        // b*512 + t
      *(short8*)&alds[slot * 8] = *(const short8*)&A[(size_t)Arow * K + col];
      int rowb = bn0 + t8 * 16 + (Ls & 15);               // gate col in [0,2048)
      *(short8*)&blds[slot * 8] = *(const short8*)&Bm[(size_t)rowb * K + col];
    }
    __syncthreads();
    short8 af[4];
    #pragma unroll
    for (int a = 0; a < 4; a++) af[a] = *(const short8*)&alds[((wm * 4 + a) * 64 + L) * 8];
    #pragma unroll
    for (int bq = 0; bq < 4; bq++) {
      short8 bfr = *(const short8*)&blds[((wn * 4 + bq) * 64 + L) * 8];
      #pragma unroll
      for (int a = 0; a < 4; a++)
        acc[a][bq] = __builtin_amdgcn_mfma_f32_16x16x32_bf16(af[a], bfr, acc[a][bq], 0, 0, 0);
    }
  }
  int lm = L >> 4, ln = L & 15;
  #pragma unroll
  for (int bq = 0; bq < 4; bq++) {
    int n = bn0 + (wn * 4 + bq) * 16 + ln;  // [0,2048)
    float bv = bptr[n];
    #pragma unroll
    for (int a = 0; a < 4; a++) {
      #pragma unroll
      for (int rr = 0; rr < 4; rr++) {
        int m = bm0 + (wm * 4 + a) * 16 + lm * 4 + rr;
        int b = m >> 6, ts = m & 63;
        xg[((size_t)(ts * 64 + b)) * 2048 + n] = f2bf(acc[a][bq][rr] + bv);
      }
    }
  }
}

// ---------------- recurrent LSTM, one chunk of 64 steps (both dirs; 64 blocks) ----------------
// block: dir d = bid>>5, slice g = bid&31 owns h-cols [g*16,g*16+16) => gate cols q*512+g*16+jj.
// h exchanged through a FRAG-MAJOR buffer at SYSTEM scope (sc0 sc1 -> Infinity Cache, coherent
// across XCDs). No fences: per-step protocol is stores -> s_waitcnt(0) -> s_barrier -> tid0
// counter RMW at L3 -> spin -> s_barrier. L2 stays warm for xg/W.
// h frag-major slot for element (m,khid): ((((m>>4)*16 + (khid>>5))*64 + (m&15) + 16*((khid>>3)&3))*8 + (khid&7)
__global__ __launch_bounds__(256) void lstm_chunk(const ushort_t* __restrict__ xg0c,
                                                  const ushort_t* __restrict__ xg1c,
                                                  const float* __restrict__ whh_f,  // layer base [2][2048][512] f32
                                                  ushort_t* __restrict__ hcL,       // [2 dir][2 buf][32768]
                                                  float* __restrict__ cstL,         // [2 dir][64][512]
                                                  ushort_t* __restrict__ outL,      // [32768][1024], col offset d*512
                                                  int* __restrict__ bar, int c) {
  __shared__ alignas(16) ushort_t wlds[32768];  // 64 KB
  int bid = blockIdx.x, d = bid >> 5, g = bid & 31, j0 = g * 16;
  int tid = threadIdx.x, L = tid & 63, w = tid >> 6;
  const float* wptr = whh_f + (size_t)d * 2048 * 512;
  #pragma unroll
  for (int it = 0; it < 16; it++) {
    int slot = it * 256 + tid;  // 0..4095
    int q = slot >> 10, kb = (slot >> 6) & 15, Ls = slot & 63;
    int gcol = q * 512 + j0 + (Ls & 15);
    int k = kb * 32 + (Ls >> 4) * 8;
    const float* src = wptr + (size_t)gcol * 512 + k;
    float4 f0 = *(const float4*)src;
    float4 f1 = *(const float4*)(src + 4);
    short8 v;
    v[0] = (short)f2bf(f0.x); v[1] = (short)f2bf(f0.y);
    v[2] = (short)f2bf(f0.z); v[3] = (short)f2bf(f0.w);
    v[4] = (short)f2bf(f1.x); v[5] = (short)f2bf(f1.y);
    v[6] = (short)f2bf(f1.z); v[7] = (short)f2bf(f1.w);
    *(short8*)&wlds[slot * 8] = v;
  }
  __syncthreads();
  const ushort_t* xgd = d ? xg1c : xg0c;
  ushort_t* hcd = hcL + (size_t)d * 2 * 32768;  // [2 parity][32768]
  int q8 = L >> 4, jj = L & 15;
  int mbase = w * 16 + q8 * 4;                  // C-layout batch-row base
  // writer slot (even-jj lanes store packed dwords for cols jj, jj+1):
  int wslot = ((w * 16 + (g >> 1)) * 64 + q8 * 4 + 16 * ((g & 1) * 2 + (jj >> 3))) * 8 + (jj & 7);
  // reader base: wave w, lane L, kb: 16B at ushort index rbase + kb*512
  int rbase = (w * 16 * 64 + L) * 8;
  float cv[4];
  #pragma unroll
  for (int rr = 0; rr < 4; rr++) cv[rr] = cstL[(size_t)d * 32768 + (mbase + rr) * 512 + j0 + jj];
  int* bptr = bar + d;

  auto ldxg = [&](int sl2, ushort_t dst[4][4]) {
    int ts2 = d ? (63 - sl2) : sl2;
    #pragma unroll
    for (int rr = 0; rr < 4; rr++) {
      const ushort_t* xrow = xgd + ((size_t)(ts2 * 64 + mbase + rr)) * 2048 + j0 + jj;
      #pragma unroll
      for (int q = 0; q < 4; q++) dst[q][rr] = xrow[q * 512];
    }
  };

  ushort_t xgu[4][4];
  ldxg(0, xgu);

  for (int sl = 0; sl < 64; sl++) {
    int s = c * 64 + sl;
    int t = d ? (511 - s) : s;
    const u64_t* h64 = (const u64_t*)(hcd + (size_t)(s & 1) * 32768);
    unsigned* h32w = (unsigned*)(hcd + (size_t)((s + 1) & 1) * 32768);
    // ---- gates = h(t) @ Whh^T : frag-major system-scope loads, double-buffered over kb ----
    u64_t ab[2][2];
    int b64 = rbase >> 2;  // u64 index; kb adds 128
    ab[0][0] = __hip_atomic_load(h64 + b64, __ATOMIC_RELAXED, __HIP_MEMORY_SCOPE_SYSTEM);
    ab[0][1] = __hip_atomic_load(h64 + b64 + 1, __ATOMIC_RELAXED, __HIP_MEMORY_SCOPE_SYSTEM);
    floatx4 acc[4] = {};
    #pragma unroll
    for (int kb = 0; kb < 16; kb++) {
      if (kb < 15) {
        int o = b64 + (kb + 1) * 128;
        ab[(kb + 1) & 1][0] = __hip_atomic_load(h64 + o, __ATOMIC_RELAXED, __HIP_MEMORY_SCOPE_SYSTEM);
        ab[(kb + 1) & 1][1] = __hip_atomic_load(h64 + o + 1, __ATOMIC_RELAXED, __HIP_MEMORY_SCOPE_SYSTEM);
      }
      union { u64_t u[2]; short8 v; } pk;
      pk.u[0] = ab[kb & 1][0];
      pk.u[1] = ab[kb & 1][1];
      short8 a = pk.v;
      #pragma unroll
      for (int q = 0; q < 4; q++) {
        short8 bfr = *(const short8*)&wlds[((q * 16 + kb) * 64 + L) * 8];
        acc[q] = __builtin_amdgcn_mfma_f32_16x16x32_bf16(a, bfr, acc[q], 0, 0, 0);
      }
    }
    // ---- pointwise LSTM cell ----
    ushort_t hbv[4];
    #pragma unroll
    for (int rr = 0; rr < 4; rr++) {
      float ii = acc[0][rr] + bf2f(xgu[0][rr]);
      float ff = acc[1][rr] + bf2f(xgu[1][rr]);
      float gg = acc[2][rr] + bf2f(xgu[2][rr]);
      float oo = acc[3][rr] + bf2f(xgu[3][rr]);
      float cc = sigf(ff) * cv[rr] + sigf(ii) * tanhf_(gg);
      cv[rr] = cc;
      hbv[rr] = f2bf(sigf(oo) * tanhf_(cc));
    }
    // ---- pack column pairs (jj, jj^1) into dwords; even-jj lanes store ----
    bool evn = (jj & 1) == 0;
    #pragma unroll
    for (int rr = 0; rr < 4; rr++) {
      unsigned mine = (unsigned)hbv[rr];
      unsigned nb = (unsigned)__shfl_xor((int)mine, 1, 64);
      if (evn) {
        unsigned packed = mine | (nb << 16);
        __hip_atomic_store(h32w + ((wslot + rr * 8) >> 1), packed,
                           __ATOMIC_RELAXED, __HIP_MEMORY_SCOPE_SYSTEM);
        int m = mbase + rr;
        *(unsigned*)&outL[((size_t)m * 512 + t) * 1024 + (d << 9) + j0 + jj] = packed;
      }
    }
    if (sl != 63) {
      ldxg(sl + 1, xgu);                 // prefetch next step's xg before the barrier
      __builtin_amdgcn_s_waitcnt(0);     // each thread drains its own vm ops (h stores at L3)
      __syncthreads();
      if (tid == 0) {
        __hip_atomic_fetch_add(bptr, 1, __ATOMIC_RELAXED, __HIP_MEMORY_SCOPE_SYSTEM);
        int target = 32 * (63 * c + sl + 1);
        int guard = 0;
        while (__hip_atomic_load(bptr, __ATOMIC_RELAXED, __HIP_MEMORY_SCOPE_SYSTEM) < target &&
               guard < (1 << 17)) guard++;
      }
      __syncthreads();
    }
  }
  #pragma unroll
  for (int rr = 0; rr < 4; rr++) cstL[(size_t)d * 32768 + (mbase + rr) * 512 + j0 + jj] = cv[rr];
}

// ---------------- emissions: [32768,1024] @ [1024,32] + b_out ----------------
__global__ __launch_bounds__(256) void emis_kernel(const ushort_t* __restrict__ out1,
                                                   const ushort_t* __restrict__ wout_bf,
                                                   const float* __restrict__ b_out,
                                                   float* __restrict__ emis) {
  int tid = threadIdx.x, L = tid & 63, w = tid >> 6;
  int bm0 = blockIdx.x * 128;
  int q8 = L >> 4, ln = L & 15;
  floatx4 acc[2][2] = {};
  #pragma unroll 4
  for (int kb = 0; kb < 32; kb++) {
    short8 a0 = *(const short8*)&out1[(size_t)(bm0 + (w * 2 + 0) * 16 + ln) * 1024 + kb * 32 + q8 * 8];
    short8 a1 = *(const short8*)&out1[(size_t)(bm0 + (w * 2 + 1) * 16 + ln) * 1024 + kb * 32 + q8 * 8];
    #pragma unroll
    for (int nt = 0; nt < 2; nt++) {
      short8 bfr = *(const short8*)&wout_bf[((size_t)(nt * 32 + kb) * 64 + L) * 8];
      acc[0][nt] = __builtin_amdgcn_mfma_f32_16x16x32_bf16(a0, bfr, acc[0][nt], 0, 0, 0);
      acc[1][nt] = __builtin_amdgcn_mfma_f32_16x16x32_bf16(a1, bfr, acc[1][nt], 0, 0, 0);
    }
  }
  #pragma unroll
  for (int mt = 0; mt < 2; mt++) {
    #pragma unroll
    for (int nt = 0; nt < 2; nt++) {
      int n = nt * 16 + ln;
      float bv = b_out[n];
      #pragma unroll
      for (int rr = 0; rr < 4; rr++) {
        int m = bm0 + (w * 2 + mt) * 16 + q8 * 4 + rr;
        emis[(size_t)m * 32 + n] = acc[mt][nt][rr] + bv;
      }
    }
  }
}

// ---------------- CRF numerator ----------------
__global__ void num_kernel(const int* __restrict__ labels, const float* __restrict__ emis,
                           const float* __restrict__ trans, const float* __restrict__ cstart,
                           const float* __restrict__ cend, float* __restrict__ num) {
  int b = blockIdx.x, tid = threadIdx.x;
  float s = 0.f;
  for (int t = tid; t < 512; t += 64) {
    int tag = labels[b * 512 + t];
    s += emis[(size_t)(b * 512 + t) * 32 + tag];
    if (t < 511) s += trans[tag * 32 + labels[b * 512 + t + 1]];
  }
  #pragma unroll
  for (int off = 32; off > 0; off >>= 1) s += __shfl_xor(s, off, 64);
  if (tid == 0) num[b] = s + cstart[labels[b * 512]] + cend[labels[b * 512 + 511]];
}

// ---------------- CRF forward scan ----------------
__global__ __launch_bounds__(64) void fwd_kernel(const float* __restrict__ emis,
                                                 const float* __restrict__ trans,
                                                 const float* __restrict__ cstart,
                                                 const float* __restrict__ cend,
                                                 const float* __restrict__ num,
                                                 float* __restrict__ perb) {
  int b = blockIdx.x, tid = threadIdx.x, j = tid & 31;
  float trj[32];
  #pragma unroll
  for (int i = 0; i < 32; i++) trj[i] = trans[i * 32 + j];
  float alpha = cstart[j] + emis[(size_t)(b * 512) * 32 + j];
  for (int t = 1; t < 512; t++) {
    float e = emis[(size_t)(b * 512 + t) * 32 + j];
    float m = -1e30f;
    float v[32];
    #pragma unroll
    for (int i = 0; i < 32; i++) {
      v[i] = __shfl(alpha, i, 32) + trj[i];
      m = fmaxf(m, v[i]);
    }
    float s = 0.f;
    #pragma unroll
    for (int i = 0; i < 32; i++) s += __expf(v[i] - m);
    alpha = __logf(s) + m + e;
  }
  float z = alpha + cend[j];
  float m2 = z;
  #pragma unroll
  for (int off = 16; off > 0; off >>= 1) m2 = fmaxf(m2, __shfl_xor(m2, off, 32));
  float s2 = __expf(z - m2);
  #pragma unroll
  for (int off = 16; off > 0; off >>= 1) s2 += __shfl_xor(s2, off, 32);
  if (tid == 0) perb[b] = num[b] - (__logf(s2) + m2);
}

__global__ void final_kernel(const float* __restrict__ perb, float* __restrict__ out) {
  int tid = threadIdx.x;
  float s = perb[tid];
  #pragma unroll
  for (int off = 32; off > 0; off >>= 1) s += __shfl_xor(s, off, 64);
  if (tid == 0) out[0] = -s;
}

// ---------------- host launch ----------------
extern "C" void kernel_launch(void* const* d_in, const int* in_sizes, int n_in,
                              void* d_out, int out_size, void* d_ws, size_t ws_size,
                              hipStream_t stream) {
  (void)in_sizes; (void)n_in; (void)out_size; (void)ws_size;
  const int* datas = (const int*)d_in[0];
  const int* labels = (const int*)d_in[1];
  const float* emb = (const float*)d_in[2];
  const float* w_ih0 = (const float*)d_in[3];
  const float* w_ih1 = (const float*)d_in[4];
  const float* w_hh = (const float*)d_in[5];
  const float* b_ih = (const float*)d_in[6];
  const float* b_hh = (const float*)d_in[7];
  const float* w_out = (const float*)d_in[8];
  const float* b_out = (const float*)d_in[9];
  const float* cstart = (const float*)d_in[10];
  const float* cend = (const float*)d_in[11];
  const float* ctrans = (const float*)d_in[12];

  char* ws = (char*)d_ws;
  ushort_t* x_bf = (ushort_t*)(ws + OFF_A);        // phases 1-2
  ushort_t* out1 = (ushort_t*)(ws + OFF_A);        // phases 3-4 (alias)
  ushort_t* out0 = (ushort_t*)(ws + OFF_OUT0);
  ushort_t* xg0c = (ushort_t*)(ws + OFF_XG);
  ushort_t* xg1c = (ushort_t*)(ws + OFF_XG + 16777216);
  float* emis = (float*)(ws + OFF_XG);             // phase 4 (alias)
  ushort_t* wih0_bf = (ushort_t*)(ws + OFF_WIH0);
  ushort_t* wih1_bf = (ushort_t*)(ws + OFF_WIH1);
  float* bias = (float*)(ws + OFF_BIAS);
  ushort_t* wout_bf = (ushort_t*)(ws + OFF_WOUT);
  ushort_t* hc0 = (ushort_t*)(ws + OFF_HC);        // layer0: [2 dir][2 buf][32768]
  ushort_t* hc1 = hc0 + 131072;                    // layer1
  float* cst0 = (float*)(ws + OFF_CST);
  float* cst1 = cst0 + 65536;
  int* bar = (int*)(ws + OFF_BAR);
  float* numb = (float*)(ws + OFF_NUM);
  float* perb = (float*)(ws + OFF_PERB);

  // zero h parity buffers, carry state, barrier counters, num/perb
  hipMemsetAsync(ws + OFF_HC, 0, OFF_END - OFF_HC, stream);

  prep_kernel<<<2048, 256, 0, stream>>>(w_ih0, w_ih1, b_ih, b_hh, w_out,
                                        wih0_bf, wih1_bf, bias, wout_bf);
  embed_kernel<<<8192, 256, 0, stream>>>(datas, emb, x_bf);

  // layer 0 (A = x_bf, K=512)
  for (int c = 0; c < 8; c++) {
    gemm_chunk<<<1024, 256, 0, stream>>>(x_bf, 512, wih0_bf, bias, xg0c, xg1c,
                                         c * 64, (7 - c) * 64);
    lstm_chunk<<<64, 256, 0, stream>>>(xg0c, xg1c, w_hh, hc0, cst0, out0, bar, c);
  }
  // layer 1 (A = out0, K=1024)
  for (int c = 0; c < 8; c++) {
    gemm_chunk<<<1024, 256, 0, stream>>>(out0, 1024, wih1_bf, bias + 4096, xg0c, xg1c,
                                         c * 64, (7 - c) * 64);
    lstm_chunk<<<64, 256, 0, stream>>>(xg0c, xg1c, w_hh + 2097152, hc1, cst1, out1,
                                       bar + 2, c);
  }

  // emissions + CRF
  emis_kernel<<<256, 256, 0, stream>>>(out1, wout_bf, b_out, emis);
  num_kernel<<<64, 64, 0, stream>>>(labels, emis, ctrans, cstart, cend, numb);
  fwd_kernel<<<64, 64, 0, stream>>>(emis, ctrans, cstart, cend, numb, perb);
  final_kernel<<<1, 64, 0, stream>>>(perb, (float*)d_out);
}

// Round 4
// 5835.163 us; speedup vs baseline: 2.9400x; 1.1928x over previous
//
#include <hip/hip_runtime.h>

typedef unsigned short ushort_t;
typedef unsigned long long u64_t;
typedef __attribute__((ext_vector_type(8))) short short8;
typedef __attribute__((ext_vector_type(4))) float floatx4;

// Problem constants: V=50000, E=512, H=512, L=32, B=64, T=512
// Chunked: NC=8 chunks of CS=64 steps.

__device__ __forceinline__ float bf2f(ushort_t u) {
  unsigned x = ((unsigned)u) << 16;
  return __builtin_bit_cast(float, x);
}
__device__ __forceinline__ ushort_t f2bf(float f) {
  unsigned x = __builtin_bit_cast(unsigned, f);
  x += 0x7FFFu + ((x >> 16) & 1u);
  return (ushort_t)(x >> 16);
}
__device__ __forceinline__ float sigf(float x) { return 1.0f / (1.0f + __expf(-x)); }
__device__ __forceinline__ float tanhf_(float x) { return 1.0f - 2.0f / (__expf(2.0f * x) + 1.0f); }

// ---------------- workspace layout (bytes), total ~173.6 MiB ----------------
static const size_t OFF_A    = 0;            // union: x_bf [32768][512] bf16 (phases 1-2)
                                             //        out1 [32768][1024] bf16 (phases 3-4)   67108864
static const size_t OFF_OUT0 = 67108864;     // out0 [32768][1024] bf16                      67108864
static const size_t OFF_XG   = 134217728;    // xg0c+xg1c [64][64][2048] bf16 each (33554432)
                                             // emis [32768][32] f32 aliases this in phase 4
static const size_t OFF_WIH0 = 167772160;    // wih0_bf [2][2048][512] bf16    4194304
static const size_t OFF_WIH1 = 171966464;    // wih1_bf [2][2048][1024] bf16   8388608
static const size_t OFF_BIAS = 180355072;    // bias [2][2][2048] f32          32768
static const size_t OFF_WOUT = 180387840;    // w_out frag-major bf16          65536
static const size_t OFF_HC   = 180453376;    // h exchange [2 layers][2 dir][2 buf][32768] bf16 frag-major
static const size_t OFF_CST  = 181501952;    // c state [2 layers][2 dir][64][512] f32        524288
static const size_t OFF_BAR  = 182026240;    // flag arrays [2 layer][2 dir][32][16] int  8192
static const size_t OFF_NUM  = 182034432;    // num[64] f32                    256
static const size_t OFF_PERB = 182034688;    // perb[64] f32                   256
static const size_t OFF_END  = 182034944;

// ---------------- prep: cast w_ih to bf16, combine biases, wout frag-major ----------------
__global__ void prep_kernel(const float* __restrict__ w_ih0, const float* __restrict__ w_ih1,
                            const float* __restrict__ b_ih, const float* __restrict__ b_hh,
                            const float* __restrict__ w_out,
                            ushort_t* __restrict__ wih0_bf, ushort_t* __restrict__ wih1_bf,
                            float* __restrict__ bias, ushort_t* __restrict__ wout_bf) {
  int idx = blockIdx.x * 256 + threadIdx.x;
  int stride = gridDim.x * 256;
  for (int i = idx; i < 2097152; i += stride) wih0_bf[i] = f2bf(w_ih0[i]);
  for (int i = idx; i < 4194304; i += stride) wih1_bf[i] = f2bf(w_ih1[i]);
  for (int i = idx; i < 8192; i += stride) bias[i] = b_ih[i] + b_hh[i];
  // w_out [1024][32] -> 16x16x32 B-operand frag-major
  for (int i = idx; i < 32768; i += stride) {
    int j = i & 7, Ls = (i >> 3) & 63, kb = (i >> 9) & 31, nt = i >> 14;
    int n = nt * 16 + (Ls & 15);
    int k = kb * 32 + ((Ls >> 4) & 3) * 8 + j;
    wout_bf[i] = f2bf(w_out[k * 32 + n]);
  }
}

// ---------------- embedding gather + cast ----------------
__global__ void embed_kernel(const int* __restrict__ datas, const float* __restrict__ emb,
                             ushort_t* __restrict__ x_bf) {
  int idx = blockIdx.x * 256 + threadIdx.x;  // < 2097152 = 32768*64
  int row = idx >> 6, sub = idx & 63;
  int tok = datas[row];
  const float4* ep = (const float4*)(emb + (size_t)tok * 512 + sub * 8);
  float4 f0 = ep[0], f1 = ep[1];
  short8 v;
  v[0] = (short)f2bf(f0.x); v[1] = (short)f2bf(f0.y);
  v[2] = (short)f2bf(f0.z); v[3] = (short)f2bf(f0.w);
  v[4] = (short)f2bf(f1.x); v[5] = (short)f2bf(f1.y);
  v[6] = (short)f2bf(f1.z); v[7] = (short)f2bf(f1.w);
  *(short8*)(x_bf + (size_t)row * 512 + sub * 8) = v;
}

// ---------------- chunked input-projection GEMM ----------------
__global__ __launch_bounds__(256) void gemm_chunk(const ushort_t* __restrict__ A, int K,
                                                  const ushort_t* __restrict__ W,
                                                  const float* __restrict__ biasL,
                                                  ushort_t* __restrict__ xg0c,
                                                  ushort_t* __restrict__ xg1c,
                                                  int t00, int t01) {
  __shared__ alignas(16) ushort_t alds[512 * 8];
  __shared__ alignas(16) ushort_t blds[512 * 8];
  int gid = blockIdx.x;
  int dir = gid >> 9, r = gid & 511;
  int mt = r & 31, ntt = r >> 5;
  int t0 = dir ? t01 : t00;
  const ushort_t* Bm = W + (size_t)dir * 2048 * K;
  const float* bptr = biasL + dir * 2048;
  ushort_t* xg = dir ? xg1c : xg0c;
  int bm0 = mt * 128, bn0 = ntt * 128;
  int tid = threadIdx.x, L = tid & 63, w = tid >> 6;
  int wm = w & 1, wn = w >> 1;
  floatx4 acc[4][4] = {};
  for (int k0 = 0; k0 < K; k0 += 32) {
    __syncthreads();
    #pragma unroll
    for (int rep = 0; rep < 2; rep++) {
      int slot = rep * 256 + tid;  // 0..511
      int t8 = slot >> 6, Ls = slot & 63;
      int col = k0 + (Ls >> 4) * 8;
      int mp = bm0 + t8 * 16 + (Ls & 15);                 // m' in [0,4096)
      int Arow = (mp >> 6) * 512 + t0 + (mp & 63);        // b*512 + t
      *(short8*)&alds[slot * 8] = *(const short8*)&A[(size_t)Arow * K + col];
      int rowb = bn0 + t8 * 16 + (Ls & 15);               // gate col in [0,2048)
      *(short8*)&blds[slot * 8] = *(const short8*)&Bm[(size_t)rowb * K + col];
    }
    __syncthreads();
    short8 af[4];
    #pragma unroll
    for (int a = 0; a < 4; a++) af[a] = *(const short8*)&alds[((wm * 4 + a) * 64 + L) * 8];
    #pragma unroll
    for (int bq = 0; bq < 4; bq++) {
      short8 bfr = *(const short8*)&blds[((wn * 4 + bq) * 64 + L) * 8];
      #pragma unroll
      for (int a = 0; a < 4; a++)
        acc[a][bq] = __builtin_amdgcn_mfma_f32_16x16x32_bf16(af[a], bfr, acc[a][bq], 0, 0, 0);
    }
  }
  int lm = L >> 4, ln = L & 15;
  #pragma unroll
  for (int bq = 0; bq < 4; bq++) {
    int n = bn0 + (wn * 4 + bq) * 16 + ln;  // [0,2048)
    float bv = bptr[n];
    #pragma unroll
    for (int a = 0; a < 4; a++) {
      #pragma unroll
      for (int rr = 0; rr < 4; rr++) {
        int m = bm0 + (wm * 4 + a) * 16 + lm * 4 + rr;
        int b = m >> 6, ts = m & 63;
        xg[((size_t)(ts * 64 + b)) * 2048 + n] = f2bf(acc[a][bq][rr] + bv);
      }
    }
  }
}

// ---------------- recurrent LSTM, one chunk of 64 steps (both dirs; 64 blocks) ----------------
// block: dir d = bid>>5, slice g = bid&31 owns h-cols [g*16,g*16+16) => gate cols q*512+g*16+jj.
// h exchanged frag-major at SYSTEM scope (coherent point). Per-step protocol:
//   h stores -> s_waitcnt(0) -> s_barrier -> tid0 stores its per-block FLAG (= step+1)
//   -> wave0 lanes poll the 32 flags in parallel (ballot) -> s_barrier.
// h loads for a step: all 32 u64 system-scope loads issued upfront (one RTT, not 16).
__global__ __launch_bounds__(256) void lstm_chunk(const ushort_t* __restrict__ xg0c,
                                                  const ushort_t* __restrict__ xg1c,
                                                  const float* __restrict__ whh_f,  // layer base [2][2048][512] f32
                                                  ushort_t* __restrict__ hcL,       // [2 dir][2 buf][32768]
                                                  float* __restrict__ cstL,         // [2 dir][64][512]
                                                  ushort_t* __restrict__ outL,      // [32768][1024], col offset d*512
                                                  int* __restrict__ barF, int c) {
  __shared__ alignas(16) ushort_t wlds[32768];  // 64 KB
  int bid = blockIdx.x, d = bid >> 5, g = bid & 31, j0 = g * 16;
  int tid = threadIdx.x, L = tid & 63, w = tid >> 6;
  const float* wptr = whh_f + (size_t)d * 2048 * 512;
  #pragma unroll
  for (int it = 0; it < 16; it++) {
    int slot = it * 256 + tid;  // 0..4095
    int q = slot >> 10, kb = (slot >> 6) & 15, Ls = slot & 63;
    int gcol = q * 512 + j0 + (Ls & 15);
    int k = kb * 32 + (Ls >> 4) * 8;
    const float* src = wptr + (size_t)gcol * 512 + k;
    float4 f0 = *(const float4*)src;
    float4 f1 = *(const float4*)(src + 4);
    short8 v;
    v[0] = (short)f2bf(f0.x); v[1] = (short)f2bf(f0.y);
    v[2] = (short)f2bf(f0.z); v[3] = (short)f2bf(f0.w);
    v[4] = (short)f2bf(f1.x); v[5] = (short)f2bf(f1.y);
    v[6] = (short)f2bf(f1.z); v[7] = (short)f2bf(f1.w);
    *(short8*)&wlds[slot * 8] = v;
  }
  __syncthreads();
  const ushort_t* xgd = d ? xg1c : xg0c;
  ushort_t* hcd = hcL + (size_t)d * 2 * 32768;  // [2 parity][32768]
  int* flg = barF + d * 512;                    // 32 flags spaced 16 ints (64B)
  int* myflag = flg + g * 16;
  int q8 = L >> 4, jj = L & 15;
  int mbase = w * 16 + q8 * 4;                  // C-layout batch-row base
  // writer slot (even-jj lanes store packed dwords for cols jj, jj+1):
  int wslot = ((w * 16 + (g >> 1)) * 64 + q8 * 4 + 16 * ((g & 1) * 2 + (jj >> 3))) * 8 + (jj & 7);
  // reader base: wave w, lane L, kb: 16B at ushort index rbase + kb*512
  int rbase = (w * 16 * 64 + L) * 8;
  float cv[4];
  #pragma unroll
  for (int rr = 0; rr < 4; rr++) cv[rr] = cstL[(size_t)d * 32768 + (mbase + rr) * 512 + j0 + jj];

  auto ldxg = [&](int sl2, ushort_t dst[4][4]) {
    int ts2 = d ? (63 - sl2) : sl2;
    #pragma unroll
    for (int rr = 0; rr < 4; rr++) {
      const ushort_t* xrow = xgd + ((size_t)(ts2 * 64 + mbase + rr)) * 2048 + j0 + jj;
      #pragma unroll
      for (int q = 0; q < 4; q++) dst[q][rr] = xrow[q * 512];
    }
  };

  ushort_t xgu[4][4];
  ldxg(0, xgu);

  for (int sl = 0; sl < 64; sl++) {
    int s = c * 64 + sl;
    int t = d ? (511 - s) : s;
    const u64_t* h64 = (const u64_t*)(hcd + (size_t)(s & 1) * 32768);
    unsigned* h32w = (unsigned*)(hcd + (size_t)((s + 1) & 1) * 32768);
    // ---- issue ALL h loads upfront (32 independent system-scope u64 loads) ----
    int b64 = rbase >> 2;  // u64 index; kb adds 128
    u64_t hv[32];
    #pragma unroll
    for (int kb = 0; kb < 16; kb++) {
      hv[2 * kb]     = __hip_atomic_load(h64 + b64 + kb * 128,     __ATOMIC_RELAXED, __HIP_MEMORY_SCOPE_SYSTEM);
      hv[2 * kb + 1] = __hip_atomic_load(h64 + b64 + kb * 128 + 1, __ATOMIC_RELAXED, __HIP_MEMORY_SCOPE_SYSTEM);
    }
    floatx4 acc[4] = {};
    #pragma unroll
    for (int kb = 0; kb < 16; kb++) {
      union { u64_t u[2]; short8 v; } pk;
      pk.u[0] = hv[2 * kb];
      pk.u[1] = hv[2 * kb + 1];
      short8 a = pk.v;
      #pragma unroll
      for (int q = 0; q < 4; q++) {
        short8 bfr = *(const short8*)&wlds[((q * 16 + kb) * 64 + L) * 8];
        acc[q] = __builtin_amdgcn_mfma_f32_16x16x32_bf16(a, bfr, acc[q], 0, 0, 0);
      }
    }
    // ---- pointwise LSTM cell ----
    ushort_t hbv[4];
    #pragma unroll
    for (int rr = 0; rr < 4; rr++) {
      float ii = acc[0][rr] + bf2f(xgu[0][rr]);
      float ff = acc[1][rr] + bf2f(xgu[1][rr]);
      float gg = acc[2][rr] + bf2f(xgu[2][rr]);
      float oo = acc[3][rr] + bf2f(xgu[3][rr]);
      float cc = sigf(ff) * cv[rr] + sigf(ii) * tanhf_(gg);
      cv[rr] = cc;
      hbv[rr] = f2bf(sigf(oo) * tanhf_(cc));
    }
    // ---- pack column pairs (jj, jj^1) into dwords; even-jj lanes store ----
    bool evn = (jj & 1) == 0;
    #pragma unroll
    for (int rr = 0; rr < 4; rr++) {
      unsigned mine = (unsigned)hbv[rr];
      unsigned nb = (unsigned)__shfl_xor((int)mine, 1, 64);
      if (evn) {
        unsigned packed = mine | (nb << 16);
        __hip_atomic_store(h32w + ((wslot + rr * 8) >> 1), packed,
                           __ATOMIC_RELAXED, __HIP_MEMORY_SCOPE_SYSTEM);
        int m = mbase + rr;
        *(unsigned*)&outL[((size_t)m * 512 + t) * 1024 + (d << 9) + j0 + jj] = packed;
      }
    }
    if (sl != 63) {
      ldxg(sl + 1, xgu);                 // prefetch next step's xg (overlaps the barrier)
      __builtin_amdgcn_s_waitcnt(0);     // drain this thread's h stores at the coherence point
      __syncthreads();                   // => all 256 threads' h stores are globally visible
      if (tid == 0)
        __hip_atomic_store(myflag, s + 1, __ATOMIC_RELAXED, __HIP_MEMORY_SCOPE_SYSTEM);
      if (tid < 64) {
        int target = s + 1, guard = 0;
        while (guard < (1 << 17)) {
          int f = __hip_atomic_load(flg + (tid & 31) * 16, __ATOMIC_RELAXED, __HIP_MEMORY_SCOPE_SYSTEM);
          if (__ballot(f >= target) == ~0ULL) break;
          guard++;
        }
      }
      __syncthreads();
    }
  }
  #pragma unroll
  for (int rr = 0; rr < 4; rr++) cstL[(size_t)d * 32768 + (mbase + rr) * 512 + j0 + jj] = cv[rr];
}

// ---------------- emissions: [32768,1024] @ [1024,32] + b_out ----------------
__global__ __launch_bounds__(256) void emis_kernel(const ushort_t* __restrict__ out1,
                                                   const ushort_t* __restrict__ wout_bf,
                                                   const float* __restrict__ b_out,
                                                   float* __restrict__ emis) {
  int tid = threadIdx.x, L = tid & 63, w = tid >> 6;
  int bm0 = blockIdx.x * 128;
  int q8 = L >> 4, ln = L & 15;
  floatx4 acc[2][2] = {};
  #pragma unroll 4
  for (int kb = 0; kb < 32; kb++) {
    short8 a0 = *(const short8*)&out1[(size_t)(bm0 + (w * 2 + 0) * 16 + ln) * 1024 + kb * 32 + q8 * 8];
    short8 a1 = *(const short8*)&out1[(size_t)(bm0 + (w * 2 + 1) * 16 + ln) * 1024 + kb * 32 + q8 * 8];
    #pragma unroll
    for (int nt = 0; nt < 2; nt++) {
      short8 bfr = *(const short8*)&wout_bf[((size_t)(nt * 32 + kb) * 64 + L) * 8];
      acc[0][nt] = __builtin_amdgcn_mfma_f32_16x16x32_bf16(a0, bfr, acc[0][nt], 0, 0, 0);
      acc[1][nt] = __builtin_amdgcn_mfma_f32_16x16x32_bf16(a1, bfr, acc[1][nt], 0, 0, 0);
    }
  }
  #pragma unroll
  for (int mt = 0; mt < 2; mt++) {
    #pragma unroll
    for (int nt = 0; nt < 2; nt++) {
      int n = nt * 16 + ln;
      float bv = b_out[n];
      #pragma unroll
      for (int rr = 0; rr < 4; rr++) {
        int m = bm0 + (w * 2 + mt) * 16 + q8 * 4 + rr;
        emis[(size_t)m * 32 + n] = acc[mt][nt][rr] + bv;
      }
    }
  }
}

// ---------------- CRF numerator ----------------
__global__ void num_kernel(const int* __restrict__ labels, const float* __restrict__ emis,
                           const float* __restrict__ trans, const float* __restrict__ cstart,
                           const float* __restrict__ cend, float* __restrict__ num) {
  int b = blockIdx.x, tid = threadIdx.x;
  float s = 0.f;
  for (int t = tid; t < 512; t += 64) {
    int tag = labels[b * 512 + t];
    s += emis[(size_t)(b * 512 + t) * 32 + tag];
    if (t < 511) s += trans[tag * 32 + labels[b * 512 + t + 1]];
  }
  #pragma unroll
  for (int off = 32; off > 0; off >>= 1) s += __shfl_xor(s, off, 64);
  if (tid == 0) num[b] = s + cstart[labels[b * 512]] + cend[labels[b * 512 + 511]];
}

// ---------------- CRF forward scan ----------------
__global__ __launch_bounds__(64) void fwd_kernel(const float* __restrict__ emis,
                                                 const float* __restrict__ trans,
                                                 const float* __restrict__ cstart,
                                                 const float* __restrict__ cend,
                                                 const float* __restrict__ num,
                                                 float* __restrict__ perb) {
  int b = blockIdx.x, tid = threadIdx.x, j = tid & 31;
  float trj[32];
  #pragma unroll
  for (int i = 0; i < 32; i++) trj[i] = trans[i * 32 + j];
  float alpha = cstart[j] + emis[(size_t)(b * 512) * 32 + j];
  for (int t = 1; t < 512; t++) {
    float e = emis[(size_t)(b * 512 + t) * 32 + j];
    float m = -1e30f;
    float v[32];
    #pragma unroll
    for (int i = 0; i < 32; i++) {
      v[i] = __shfl(alpha, i, 32) + trj[i];
      m = fmaxf(m, v[i]);
    }
    float s = 0.f;
    #pragma unroll
    for (int i = 0; i < 32; i++) s += __expf(v[i] - m);
    alpha = __logf(s) + m + e;
  }
  float z = alpha + cend[j];
  float m2 = z;
  #pragma unroll
  for (int off = 16; off > 0; off >>= 1) m2 = fmaxf(m2, __shfl_xor(m2, off, 32));
  float s2 = __expf(z - m2);
  #pragma unroll
  for (int off = 16; off > 0; off >>= 1) s2 += __shfl_xor(s2, off, 32);
  if (tid == 0) perb[b] = num[b] - (__logf(s2) + m2);
}

__global__ void final_kernel(const float* __restrict__ perb, float* __restrict__ out) {
  int tid = threadIdx.x;
  float s = perb[tid];
  #pragma unroll
  for (int off = 32; off > 0; off >>= 1) s += __shfl_xor(s, off, 64);
  if (tid == 0) out[0] = -s;
}

// ---------------- host launch ----------------
extern "C" void kernel_launch(void* const* d_in, const int* in_sizes, int n_in,
                              void* d_out, int out_size, void* d_ws, size_t ws_size,
                              hipStream_t stream) {
  (void)in_sizes; (void)n_in; (void)out_size; (void)ws_size;
  const int* datas = (const int*)d_in[0];
  const int* labels = (const int*)d_in[1];
  const float* emb = (const float*)d_in[2];
  const float* w_ih0 = (const float*)d_in[3];
  const float* w_ih1 = (const float*)d_in[4];
  const float* w_hh = (const float*)d_in[5];
  const float* b_ih = (const float*)d_in[6];
  const float* b_hh = (const float*)d_in[7];
  const float* w_out = (const float*)d_in[8];
  const float* b_out = (const float*)d_in[9];
  const float* cstart = (const float*)d_in[10];
  const float* cend = (const float*)d_in[11];
  const float* ctrans = (const float*)d_in[12];

  char* ws = (char*)d_ws;
  ushort_t* x_bf = (ushort_t*)(ws + OFF_A);        // phases 1-2
  ushort_t* out1 = (ushort_t*)(ws + OFF_A);        // phases 3-4 (alias)
  ushort_t* out0 = (ushort_t*)(ws + OFF_OUT0);
  ushort_t* xg0c = (ushort_t*)(ws + OFF_XG);
  ushort_t* xg1c = (ushort_t*)(ws + OFF_XG + 16777216);
  float* emis = (float*)(ws + OFF_XG);             // phase 4 (alias)
  ushort_t* wih0_bf = (ushort_t*)(ws + OFF_WIH0);
  ushort_t* wih1_bf = (ushort_t*)(ws + OFF_WIH1);
  float* bias = (float*)(ws + OFF_BIAS);
  ushort_t* wout_bf = (ushort_t*)(ws + OFF_WOUT);
  ushort_t* hc0 = (ushort_t*)(ws + OFF_HC);        // layer0: [2 dir][2 buf][32768]
  ushort_t* hc1 = hc0 + 131072;                    // layer1
  float* cst0 = (float*)(ws + OFF_CST);
  float* cst1 = cst0 + 65536;
  int* bar = (int*)(ws + OFF_BAR);                 // [2 layer][2 dir][32][16] ints
  float* numb = (float*)(ws + OFF_NUM);
  float* perb = (float*)(ws + OFF_PERB);

  // zero h parity buffers, carry state, flags, num/perb
  hipMemsetAsync(ws + OFF_HC, 0, OFF_END - OFF_HC, stream);

  prep_kernel<<<2048, 256, 0, stream>>>(w_ih0, w_ih1, b_ih, b_hh, w_out,
                                        wih0_bf, wih1_bf, bias, wout_bf);
  embed_kernel<<<8192, 256, 0, stream>>>(datas, emb, x_bf);

  // layer 0 (A = x_bf, K=512)
  for (int c = 0; c < 8; c++) {
    gemm_chunk<<<1024, 256, 0, stream>>>(x_bf, 512, wih0_bf, bias, xg0c, xg1c,
                                         c * 64, (7 - c) * 64);
    lstm_chunk<<<64, 256, 0, stream>>>(xg0c, xg1c, w_hh, hc0, cst0, out0, bar, c);
  }
  // layer 1 (A = out0, K=1024)
  for (int c = 0; c < 8; c++) {
    gemm_chunk<<<1024, 256, 0, stream>>>(out0, 1024, wih1_bf, bias + 4096, xg0c, xg1c,
                                         c * 64, (7 - c) * 64);
    lstm_chunk<<<64, 256, 0, stream>>>(xg0c, xg1c, w_hh + 2097152, hc1, cst1, out1,
                                       bar + 1024, c);
  }

  // emissions + CRF
  emis_kernel<<<256, 256, 0, stream>>>(out1, wout_bf, b_out, emis);
  num_kernel<<<64, 64, 0, stream>>>(labels, emis, ctrans, cstart, cend, numb);
  fwd_kernel<<<64, 64, 0, stream>>>(emis, ctrans, cstart, cend, numb, perb);
  final_kernel<<<1, 64, 0, stream>>>(perb, (float*)d_out);
}